// Round 1
// baseline (204.944 us; speedup 1.0000x reference)
//
#include <hip/hip_runtime.h>
#include <hip/hip_bf16.h>
#include <hip/hip_fp16.h>

// GCN 2-layer: out = Ahat * relu(Ahat*(X W1)+b1) * W2 + b2
// Round 14: padded CSR + wide gathers.
//  - CSR rows padded to multiples of 8 edges (pad src = n -> zero row), rows
//    8-aligned via per-bucket static slack (PADSTRIDE). rend[] replaces
//    row_ptr[d+1] so buckets may leave gaps.
//  - agg64: 8 rows/wave, 8 lanes/row, half8 (16B) per lane. Batch of 8 edges =
//    2 aligned int4 index broadcasts + 8x16B gathers (was 8 scalar idx loads +
//    8x8B gathers). Next batch's indices prefetched under current gathers.
//  - agg32: 16 rows/wave, 4 lanes/row, half8. Same batch structure.
//  - build pipeline unchanged except bucket_csr (padded scan + pad fill).

#define N_FEAT_IN 64
#define B2SHIFT 9        // 512 dst nodes per coarse bucket
#define CHUNK 4096       // edges per block in pass A/B
#define PADSTRIDE 3592   // per-bucket csr slack: 512 rows * 7 max pad, 8-aligned

struct alignas(8) half4 { __half2 lo, hi; };
struct alignas(16) half8 { __half2 h[4]; };

// ---- pass A: per-chunk bucket histogram (LDS, no global atomics) ----
__global__ __launch_bounds__(1024) void passA_hist(const int* __restrict__ dst,
                                                   int* __restrict__ H, int E) {
    __shared__ int h[256];
    int t = threadIdx.x;
    if (t < 256) h[t] = 0;
    __syncthreads();
    int base = blockIdx.x * CHUNK;
    int end = min(base + CHUNK, E);
    for (int i = base + t; i < end; i += 1024)
        atomicAdd(&h[dst[i] >> B2SHIFT], 1);
    __syncthreads();
    if (t < 256) H[blockIdx.x * 256 + t] = h[t];
}

// ---- col_scan_a: one block per column; exclusive scan over NR rows ----
__global__ __launch_bounds__(512) void col_scan_a(int* __restrict__ H,
                                                  int* __restrict__ ctot, int NR) {
    __shared__ int s[512];
    int b = blockIdx.x;
    int t = threadIdx.x;
    int v = (t < NR) ? H[t * 256 + b] : 0;
    s[t] = v;
    __syncthreads();
    for (int off = 1; off < 512; off <<= 1) {
        int a = (t >= off) ? s[t - off] : 0;
        __syncthreads();
        s[t] += a;
        __syncthreads();
    }
    if (t < NR) H[t * 256 + b] = s[t] - v;
    if (t == 511) ctot[b] = s[511];
}

// ---- col_scan_b: scan column totals -> per-bucket bases; row_ptr[n]=E ----
__global__ __launch_bounds__(256) void col_scan_b(const int* __restrict__ ctot,
                                                  int* __restrict__ cbase,
                                                  int* __restrict__ bbase,
                                                  int* __restrict__ row_ptr,
                                                  int NB, int n, int E) {
    __shared__ int s[256];
    int t = threadIdx.x;
    int v = ctot[t];
    s[t] = v;
    __syncthreads();
    for (int off = 1; off < 256; off <<= 1) {
        int a = (t >= off) ? s[t - off] : 0;
        __syncthreads();
        s[t] += a;
        __syncthreads();
    }
    int e = s[t] - v;
    cbase[t] = e;
    if (t < NB) bbase[t] = e;
    if (t == 0) { bbase[NB] = E; row_ptr[n] = E; }
}

// ---- pass B: place packed edges into private per-chunk runs ----
__global__ __launch_bounds__(1024) void passB_place(const int* __restrict__ src,
                                                    const int* __restrict__ dst,
                                                    const int* __restrict__ H,
                                                    const int* __restrict__ cbase,
                                                    unsigned* __restrict__ bedges, int E) {
    __shared__ int cur[256];
    int t = threadIdx.x;
    if (t < 256) cur[t] = H[blockIdx.x * 256 + t] + cbase[t];
    __syncthreads();
    int base = blockIdx.x * CHUNK;
    int end = min(base + CHUNK, E);
    for (int i = base + t; i < end; i += 1024) {
        int d = dst[i];
        int p = atomicAdd(&cur[d >> B2SHIFT], 1);  // LDS atomic
        bedges[p] = ((unsigned)src[i] << B2SHIFT) | (unsigned)(d & 511);
    }
}

// ---- merged: per-bucket hist -> padded scan -> row_ptr/rend/dinv -> scatter ----
// csr rows padded to multiples of 8 (pad entries = n -> zero row); row starts
// 8-aligned: pbase = align8(bbase[b]) + b*PADSTRIDE.
__global__ __launch_bounds__(1024) void bucket_csr(const int* __restrict__ bbase,
                                                   const unsigned* __restrict__ bedges,
                                                   int* __restrict__ row_ptr,
                                                   int* __restrict__ rend,
                                                   float* __restrict__ dinv,
                                                   int* __restrict__ csr_src, int n) {
    __shared__ int lh[512];
    __shared__ int cur[512];
    int t = threadIdx.x;
    if (t < 512) lh[t] = 0;
    __syncthreads();
    int b = blockIdx.x;
    int beg = bbase[b], end = bbase[b + 1];
    for (int i = beg + t; i < end; i += 1024)
        atomicAdd(&lh[bedges[i] & 511], 1);
    __syncthreads();
    int c = (t < 512) ? lh[t] : 0;       // true degree (no self-loop)
    __syncthreads();
    int cp = (c + 7) & ~7;               // padded degree
    if (t < 512) lh[t] = cp;
    __syncthreads();
    for (int off = 1; off < 512; off <<= 1) {
        int a = (t < 512 && t >= off) ? lh[t - off] : 0;
        __syncthreads();
        if (t < 512) lh[t] += a;
        __syncthreads();
    }
    int pb = ((beg + 7) & ~7) + b * PADSTRIDE;
    if (t < 512) {
        int d = (b << B2SHIFT) + t;
        int rbeg = pb + lh[t] - cp;      // 8-aligned exclusive padded offset
        cur[t] = rbeg;
        if (d < n) {
            row_ptr[d] = rbeg;
            rend[d] = rbeg + cp;
            dinv[d] = rsqrtf((float)c + 1.0f);
            for (int i = c; i < cp; ++i) csr_src[rbeg + i] = n;  // pad -> zero row
        }
    }
    __syncthreads();
    for (int i = beg + t; i < end; i += 1024) {
        unsigned v = bedges[i];
        int p = atomicAdd(&cur[v & 511], 1);  // LDS atomic
        csr_src[p] = (int)(v >> B2SHIFT);
    }
}

// ---- GEMM layer1: xs1[n+1,64] fp16 = half( dinv[row] * (X W1) ); pad row 0 ----
__global__ __launch_bounds__(256) void gemm64(const float* __restrict__ A,
                                              const float* __restrict__ W,
                                              const float* __restrict__ dinv,
                                              __half* __restrict__ outh, int n) {
    constexpr int K = 64, FO = 64, CPT = 16;
    __shared__ float As[64][K + 4];
    __shared__ float Ws[K][FO];

    const int t = threadIdx.x;
    const int r0 = blockIdx.x * 64;

    if (blockIdx.x == 0 && t < FO)
        outh[(size_t)n * FO + t] = __float2half(0.f);

    for (int i = t; i < K * FO / 4; i += 256) {
        int k = i / (FO / 4);
        int c4 = (i % (FO / 4)) * 4;
        *(float4*)&Ws[k][c4] = *(const float4*)&W[k * FO + c4];
    }
    for (int i = t; i < 1024; i += 256) {
        int row = i / 16;
        int c4 = (i % 16) * 4;
        int g = r0 + row;
        float4 v = make_float4(0.f, 0.f, 0.f, 0.f);
        if (g < n) v = *(const float4*)&A[(size_t)g * K + c4];
        *(float4*)&As[row][c4] = v;
    }
    __syncthreads();

    const int row = t >> 2;
    const int c0 = (t & 3) * CPT;
    float acc[CPT];
#pragma unroll
    for (int j = 0; j < CPT; ++j) acc[j] = 0.f;
#pragma unroll
    for (int k = 0; k < K; ++k) {
        float xv = As[row][k];
#pragma unroll
        for (int j = 0; j < CPT; ++j) acc[j] = fmaf(xv, Ws[k][c0 + j], acc[j]);
    }

    int g = r0 + row;
    if (g < n) {
        float sc = dinv[g];
#pragma unroll
        for (int j4 = 0; j4 < CPT; j4 += 4) {
            half4 h;
            h.lo = __floats2half2_rn(acc[j4] * sc, acc[j4 + 1] * sc);
            h.hi = __floats2half2_rn(acc[j4 + 2] * sc, acc[j4 + 3] * sc);
            *(half4*)&outh[(size_t)g * FO + c0 + j4] = h;
        }
    }
}

#define ACC8(v)                                                       \
    {                                                                 \
        float2 f0 = __half22float2((v).h[0]);                         \
        float2 f1 = __half22float2((v).h[1]);                         \
        float2 f2 = __half22float2((v).h[2]);                         \
        float2 f3 = __half22float2((v).h[3]);                         \
        a0 += f0.x; a1 += f0.y; a2 += f1.x; a3 += f1.y;               \
        a4 += f2.x; a5 += f2.y; a6 += f3.x; a7 += f3.y;               \
    }

// ---- agg64: 8 rows/wave, 8 lanes/row, half8/lane; t = relu(dinv*acc+b1) ----
// Padded rows: batch of 8 edges = 2 aligned int4 index loads + 8x16B gathers.
__global__ __launch_bounds__(256) void agg64(const int* __restrict__ row_ptr,
                                             const int* __restrict__ rend,
                                             const int* __restrict__ csr_src,
                                             const float* __restrict__ dinv,
                                             const __half* __restrict__ xs1,
                                             const float* __restrict__ b1,
                                             __half* __restrict__ th, int n) {
    int d = blockIdx.x * 32 + (threadIdx.x >> 3);  // 32 rows/block
    if (d >= n) return;
    int c = threadIdx.x & 7;                       // half8 slice (feats 8c..8c+7)
    const half8* __restrict__ xrow = (const half8*)xs1 + c;  // row stride 8 half8

    half8 sv = xrow[(size_t)d * 8];                // self-loop
    float a0, a1, a2, a3, a4, a5, a6, a7;
    {
        float2 f0 = __half22float2(sv.h[0]), f1 = __half22float2(sv.h[1]);
        float2 f2 = __half22float2(sv.h[2]), f3 = __half22float2(sv.h[3]);
        a0 = f0.x; a1 = f0.y; a2 = f1.x; a3 = f1.y;
        a4 = f2.x; a5 = f2.y; a6 = f3.x; a7 = f3.y;
    }

    int beg = row_ptr[d];
    int end = rend[d];
    if (beg < end) {
        int4 ia = *(const int4*)&csr_src[beg];
        int4 ib = *(const int4*)&csr_src[beg + 4];
        int jb = beg;
        for (;;) {
            int jn = jb + 8;
            bool more = jn < end;
            int js = more ? jn : beg;              // prefetch (aligned) next batch
            int4 na = *(const int4*)&csr_src[js];
            int4 nb = *(const int4*)&csr_src[js + 4];
            half8 v0 = xrow[(size_t)ia.x * 8];
            half8 v1 = xrow[(size_t)ia.y * 8];
            half8 v2 = xrow[(size_t)ia.z * 8];
            half8 v3 = xrow[(size_t)ia.w * 8];
            half8 v4 = xrow[(size_t)ib.x * 8];
            half8 v5 = xrow[(size_t)ib.y * 8];
            half8 v6 = xrow[(size_t)ib.z * 8];
            half8 v7 = xrow[(size_t)ib.w * 8];
            ACC8(v0); ACC8(v1); ACC8(v2); ACC8(v3);
            ACC8(v4); ACC8(v5); ACC8(v6); ACC8(v7);
            if (!more) break;
            jb = jn; ia = na; ib = nb;
        }
    }

    float di = dinv[d];
    float4 ba = *(const float4*)&b1[8 * c];
    float4 bb = *(const float4*)&b1[8 * c + 4];
    float t0 = fmaxf(fmaf(di, a0, ba.x), 0.f);
    float t1 = fmaxf(fmaf(di, a1, ba.y), 0.f);
    float t2 = fmaxf(fmaf(di, a2, ba.z), 0.f);
    float t3 = fmaxf(fmaf(di, a3, ba.w), 0.f);
    float t4 = fmaxf(fmaf(di, a4, bb.x), 0.f);
    float t5 = fmaxf(fmaf(di, a5, bb.y), 0.f);
    float t6 = fmaxf(fmaf(di, a6, bb.z), 0.f);
    float t7 = fmaxf(fmaf(di, a7, bb.w), 0.f);
    half8 o;
    o.h[0] = __floats2half2_rn(t0, t1);
    o.h[1] = __floats2half2_rn(t2, t3);
    o.h[2] = __floats2half2_rn(t4, t5);
    o.h[3] = __floats2half2_rn(t6, t7);
    *(half8*)&th[(size_t)d * 64 + 8 * c] = o;
}

// ---- gemm32h: xs2[n+1,32] fp16 = half( dinv[row] * (t[n,64] W2) ); pad row ----
__global__ __launch_bounds__(256) void gemm32h(const __half* __restrict__ Ah,
                                               const float* __restrict__ W,
                                               const float* __restrict__ dinv,
                                               __half* __restrict__ outh, int n) {
    constexpr int K = 64, FO = 32, CPT = 8;
    __shared__ float As[64][K + 4];
    __shared__ float Ws[K][FO];

    const int t = threadIdx.x;
    const int r0 = blockIdx.x * 64;

    if (blockIdx.x == 0 && t < FO)
        outh[(size_t)n * FO + t] = __float2half(0.f);

    for (int i = t; i < K * FO / 4; i += 256) {
        int k = i / (FO / 4);
        int c4 = (i % (FO / 4)) * 4;
        *(float4*)&Ws[k][c4] = *(const float4*)&W[k * FO + c4];
    }
    for (int i = t; i < 1024; i += 256) {
        int row = i / 16;
        int c4 = (i % 16) * 4;
        int g = r0 + row;
        float4 v = make_float4(0.f, 0.f, 0.f, 0.f);
        if (g < n) {
            half4 hv = *(const half4*)&Ah[(size_t)g * K + c4];
            float2 lo = __half22float2(hv.lo), hi = __half22float2(hv.hi);
            v = make_float4(lo.x, lo.y, hi.x, hi.y);
        }
        *(float4*)&As[row][c4] = v;
    }
    __syncthreads();

    const int row = t >> 2;
    const int c0 = (t & 3) * CPT;
    float acc[CPT];
#pragma unroll
    for (int j = 0; j < CPT; ++j) acc[j] = 0.f;
#pragma unroll
    for (int k = 0; k < K; ++k) {
        float xv = As[row][k];
#pragma unroll
        for (int j = 0; j < CPT; ++j) acc[j] = fmaf(xv, Ws[k][c0 + j], acc[j]);
    }

    int g = r0 + row;
    if (g < n) {
        float sc = dinv[g];
#pragma unroll
        for (int j4 = 0; j4 < CPT; j4 += 4) {
            half4 h;
            h.lo = __floats2half2_rn(acc[j4] * sc, acc[j4 + 1] * sc);
            h.hi = __floats2half2_rn(acc[j4 + 2] * sc, acc[j4 + 3] * sc);
            *(half4*)&outh[(size_t)g * FO + c0 + j4] = h;
        }
    }
}

// ---- agg32: 16 rows/wave, 4 lanes/row, half8/lane; out = dinv*acc + b2 ----
__global__ __launch_bounds__(256) void agg32(const int* __restrict__ row_ptr,
                                             const int* __restrict__ rend,
                                             const int* __restrict__ csr_src,
                                             const float* __restrict__ dinv,
                                             const __half* __restrict__ xs2,
                                             const float* __restrict__ b2,
                                             float* __restrict__ out, int n) {
    int d = blockIdx.x * 64 + (threadIdx.x >> 2);  // 64 rows/block
    if (d >= n) return;
    int c = threadIdx.x & 3;                       // half8 slice (feats 8c..8c+7)
    const half8* __restrict__ xrow = (const half8*)xs2 + c;  // row stride 4 half8

    half8 sv = xrow[(size_t)d * 4];                // self-loop
    float a0, a1, a2, a3, a4, a5, a6, a7;
    {
        float2 f0 = __half22float2(sv.h[0]), f1 = __half22float2(sv.h[1]);
        float2 f2 = __half22float2(sv.h[2]), f3 = __half22float2(sv.h[3]);
        a0 = f0.x; a1 = f0.y; a2 = f1.x; a3 = f1.y;
        a4 = f2.x; a5 = f2.y; a6 = f3.x; a7 = f3.y;
    }

    int beg = row_ptr[d];
    int end = rend[d];
    if (beg < end) {
        int4 ia = *(const int4*)&csr_src[beg];
        int4 ib = *(const int4*)&csr_src[beg + 4];
        int jb = beg;
        for (;;) {
            int jn = jb + 8;
            bool more = jn < end;
            int js = more ? jn : beg;
            int4 na = *(const int4*)&csr_src[js];
            int4 nb = *(const int4*)&csr_src[js + 4];
            half8 v0 = xrow[(size_t)ia.x * 4];
            half8 v1 = xrow[(size_t)ia.y * 4];
            half8 v2 = xrow[(size_t)ia.z * 4];
            half8 v3 = xrow[(size_t)ia.w * 4];
            half8 v4 = xrow[(size_t)ib.x * 4];
            half8 v5 = xrow[(size_t)ib.y * 4];
            half8 v6 = xrow[(size_t)ib.z * 4];
            half8 v7 = xrow[(size_t)ib.w * 4];
            ACC8(v0); ACC8(v1); ACC8(v2); ACC8(v3);
            ACC8(v4); ACC8(v5); ACC8(v6); ACC8(v7);
            if (!more) break;
            jb = jn; ia = na; ib = nb;
        }
    }

    float di = dinv[d];
    float4 ba = *(const float4*)&b2[8 * c];
    float4 bb = *(const float4*)&b2[8 * c + 4];
    float4 r0, r1;
    r0.x = fmaf(di, a0, ba.x);
    r0.y = fmaf(di, a1, ba.y);
    r0.z = fmaf(di, a2, ba.z);
    r0.w = fmaf(di, a3, ba.w);
    r1.x = fmaf(di, a4, bb.x);
    r1.y = fmaf(di, a5, bb.y);
    r1.z = fmaf(di, a6, bb.z);
    r1.w = fmaf(di, a7, bb.w);
    *(float4*)&out[(size_t)d * 32 + 8 * c] = r0;
    *(float4*)&out[(size_t)d * 32 + 8 * c + 4] = r1;
}

extern "C" void kernel_launch(void* const* d_in, const int* in_sizes, int n_in,
                              void* d_out, int out_size, void* d_ws, size_t ws_size,
                              hipStream_t stream) {
    const float* x  = (const float*)d_in[0];   // [n, 64]
    const int*   ei = (const int*)d_in[1];     // [2, E]
    const float* W1 = (const float*)d_in[2];   // [64, 64]
    const float* b1 = (const float*)d_in[3];   // [64]
    const float* W2 = (const float*)d_in[4];   // [64, 32]
    const float* b2 = (const float*)d_in[5];   // [32]
    float* out = (float*)d_out;                // [n, 32]

    const int n = in_sizes[0] / N_FEAT_IN;     // 100000
    const int E = in_sizes[1] / 2;             // 1600000
    const int* srcI = ei;
    const int* dstI = ei + E;

    const int NB = (n + 511) >> B2SHIFT;       // 196 coarse buckets
    const int NR = (E + CHUNK - 1) / CHUNK;    // 391 chunks

    // workspace layout (256B aligned)
    char* ws = (char*)d_ws;
    size_t off = 0;
    auto alloc = [&](size_t bytes) {
        void* p = ws + off;
        off += (bytes + 255) & ~(size_t)255;
        return p;
    };
    float*    dinv    = (float*)alloc((size_t)n * 4);
    int*      row_ptr = (int*)alloc((size_t)(n + 1) * 4);
    int*      rend    = (int*)alloc((size_t)n * 4);
    int*      bbase   = (int*)alloc((size_t)(NB + 1) * 4);
    int*      ctot    = (int*)alloc((size_t)256 * 4);
    int*      cbase   = (int*)alloc((size_t)256 * 4);
    int*      H       = (int*)alloc((size_t)NR * 256 * 4);        // ~400KB
    unsigned* bedges  = (unsigned*)alloc((size_t)E * 4);
    int*      csr_src = (int*)alloc((size_t)(E + (size_t)NB * PADSTRIDE + 16) * 4);
    __half*   xs1     = (__half*)alloc((size_t)(n + 1) * 64 * 2); // +pad row
    __half*   th      = (__half*)alloc((size_t)n * 64 * 2);       // relu'd t
    __half*   xs2     = (__half*)alloc((size_t)(n + 1) * 32 * 2); // +pad row

    // 1) atomic-free bucket sort by dst>>9
    passA_hist<<<NR, 1024, 0, stream>>>(dstI, H, E);
    col_scan_a<<<256, 512, 0, stream>>>(H, ctot, NR);
    col_scan_b<<<1, 256, 0, stream>>>(ctot, cbase, bbase, row_ptr, NB, n, E);
    passB_place<<<NR, 1024, 0, stream>>>(srcI, dstI, H, cbase, bedges, E);

    // 2) merged: padded row_ptr/rend + dinv + CSR scatter (+pad fill)
    bucket_csr<<<NB, 1024, 0, stream>>>(bbase, bedges, row_ptr, rend, dinv, csr_src, n);

    // 3) layer 1 GEMM: xs1 = half(dinv .* (X W1))
    gemm64<<<(n + 63) / 64, 256, 0, stream>>>(x, W1, dinv, xs1, n);

    // 4) layer-1 aggregate: t = relu(dinv*(gather+self) + b1)
    agg64<<<(n + 31) / 32, 256, 0, stream>>>(row_ptr, rend, csr_src, dinv, xs1, b1, th, n);

    // 5) layer-2 transform: xs2 = half(dinv .* (t W2))
    gemm32h<<<(n + 63) / 64, 256, 0, stream>>>(th, W2, dinv, xs2, n);

    // 6) layer-2 aggregate -> out
    agg32<<<(n + 63) / 64, 256, 0, stream>>>(row_ptr, rend, csr_src, dinv, xs2, b2, out, n);
}